// Round 5
// baseline (224.835 us; speedup 1.0000x reference)
//
#include <hip/hip_runtime.h>
#include <hip/hip_bf16.h>
#include <math.h>

#define F 8
#define C 4096
#define NPAIR 36            // F*(F+1)/2 pairs with i<=j
#define EPSF 1e-8f
#define NBLK 1024           // pair grid: 256 row-groups x 4 q-quarters
#define QQ   1024           // q-quarter length; 8 factors * 1024 * 4B = 32 KB LDS
#define NQD  4              // number of q-quarters

// ws layout (floats):
//   Gpart : [NPAIR][NBLK]      per-block partial G_ij        (36 K floats)
//   spart : [NQD][F][C]        quarter-partial row sums      (128 K floats)
// Every element is written by pair_kernel before finish_kernel reads it,
// so no zero-init kernel is needed (ws is 0xAA-poisoned each call).

__device__ __forceinline__ float wave_reduce(float v) {
    #pragma unroll
    for (int off = 32; off > 0; off >>= 1) v += __shfl_down(v, off, 64);
    return v;
}

__device__ __forceinline__ float fast_sqrt(float v) {
    return __builtin_amdgcn_sqrtf(v);
}

// Each wave owns 4 rows p and one q-quarter: the staged q-vector v[8] is
// reused across 4 rows (LDS bytes/position 32B -> 8B) and the 4 row
// computations are independent (deep ILP). g[36] is a global (p,q) sum so it
// is shared across rows. VGPR budget: g36+rs32+xp32+v8+d8+addr ~ 126.
__global__ __launch_bounds__(256, 4) void pair_kernel(const float* __restrict__ x,
                                                      float* __restrict__ Gpart,
                                                      float* __restrict__ spart) {
    __shared__ __align__(16) float xs[F * QQ];     // 32 KB
    __shared__ float red[4][NPAIR];
    const int tid  = threadIdx.x;
    const int lane = tid & 63;
    const int wave = tid >> 6;
    const int qd   = blockIdx.x >> 8;              // q-quarter 0..3
    const int rq   = blockIdx.x & 255;             // row-group (16 rows)
    const int p0   = rq * 16 + wave * 4;           // this wave's 4 rows

    // stage this quarter: 8 factors x 1024 floats = 2048 float4, 8/thread
    const float4* xg = (const float4*)x;
    for (int i = tid; i < F * (QQ / 4); i += 256) {
        const int f  = i >> 8;                     // / (QQ/4)
        const int q4 = i & (QQ / 4 - 1);
        ((float4*)xs)[i] = xg[f * (C / 4) + qd * (QQ / 4) + q4];
    }

    float xp[4][F];
    #pragma unroll
    for (int r = 0; r < 4; ++r)
        #pragma unroll
        for (int f = 0; f < F; ++f) xp[r][f] = x[f * C + p0 + r];

    float g[NPAIR];
    #pragma unroll
    for (int k = 0; k < NPAIR; ++k) g[k] = 0.0f;
    float rs[4][F];
    #pragma unroll
    for (int r = 0; r < 4; ++r)
        #pragma unroll
        for (int f = 0; f < F; ++f) rs[r][f] = 0.0f;

    __syncthreads();

    for (int qt = 0; qt < QQ / 64; ++qt) {         // 16 iterations
        const int qi = qt * 64 + lane;
        float v[F];
        #pragma unroll
        for (int f = 0; f < F; ++f) v[f] = xs[f * QQ + qi];

        #pragma unroll
        for (int r = 0; r < 4; ++r) {
            float d[F];
            #pragma unroll
            for (int f = 0; f < F; ++f) {
                d[f] = xp[r][f] - v[f];
                rs[r][f] += __builtin_fabsf(d[f]);
            }
            int k = 0;
            #pragma unroll
            for (int i = 0; i < F; ++i)
                #pragma unroll
                for (int j = i; j < F; ++j) {
                    g[k] = __builtin_fmaf(__builtin_fabsf(d[i]), __builtin_fabsf(d[j]), g[k]);
                    ++k;
                }
        }
    }

    // wave-level reduction (each wave owns its 4 rows exclusively)
    #pragma unroll
    for (int r = 0; r < 4; ++r)
        #pragma unroll
        for (int f = 0; f < F; ++f) rs[r][f] = wave_reduce(rs[r][f]);
    #pragma unroll
    for (int k = 0; k < NPAIR; ++k) g[k] = wave_reduce(g[k]);

    if (lane == 0) {
        #pragma unroll
        for (int r = 0; r < 4; ++r)
            #pragma unroll
            for (int f = 0; f < F; ++f)
                spart[(qd * F + f) * C + p0 + r] = rs[r][f];
        #pragma unroll
        for (int k = 0; k < NPAIR; ++k) red[wave][k] = g[k];
    }
    __syncthreads();
    if (tid < NPAIR)
        Gpart[tid * NBLK + blockIdx.x] =
            red[0][tid] + red[1][tid] + red[2][tid] + red[3][tid];
}

// 1024 threads = 16 waves. Phase A: assemble full row sums from the 4
// quarter-partials, accumulate D (36 dots) and T (8 totals). Phase B: wave k
// reduces Gpart rows k, k+16, k+32. Scalar epilogue on t0.
__global__ __launch_bounds__(1024) void finish_kernel(const float* __restrict__ Gpart,
                                                      const float* __restrict__ spart,
                                                      float* __restrict__ out) {
    const int tid  = threadIdx.x;
    const int lane = tid & 63;
    const int wave = tid >> 6;      // 0..15

    __shared__ float redD[16][NPAIR];
    __shared__ float redT[16][F];
    __shared__ float Gs[NPAIR];
    __shared__ float Dt[NPAIR];
    __shared__ float Tt[F];

    float D[NPAIR], T[F];
    #pragma unroll
    for (int k = 0; k < NPAIR; ++k) D[k] = 0.0f;
    #pragma unroll
    for (int f = 0; f < F; ++f) T[f] = 0.0f;

    #pragma unroll
    for (int it = 0; it < C / 1024; ++it) {        // 4 iterations
        const int p = it * 1024 + tid;
        float sv[F];
        #pragma unroll
        for (int f = 0; f < F; ++f) {
            float s = spart[f * C + p];
            #pragma unroll
            for (int qd = 1; qd < NQD; ++qd) s += spart[(qd * F + f) * C + p];
            sv[f] = s;
            T[f] += s;
        }
        int k = 0;
        #pragma unroll
        for (int i = 0; i < F; ++i)
            #pragma unroll
            for (int j = i; j < F; ++j) { D[k] += sv[i] * sv[j]; ++k; }
    }
    #pragma unroll
    for (int k = 0; k < NPAIR; ++k) D[k] = wave_reduce(D[k]);
    #pragma unroll
    for (int f = 0; f < F; ++f) T[f] = wave_reduce(T[f]);
    if (lane == 0) {
        #pragma unroll
        for (int k = 0; k < NPAIR; ++k) redD[wave][k] = D[k];
        #pragma unroll
        for (int f = 0; f < F; ++f) redT[wave][f] = T[f];
    }

    // Phase B: G rows
    for (int k = wave; k < NPAIR; k += 16) {
        float s = 0.0f;
        #pragma unroll
        for (int it = 0; it < NBLK / 64; ++it) s += Gpart[k * NBLK + it * 64 + lane];
        s = wave_reduce(s);
        if (lane == 0) Gs[k] = s;
    }
    __syncthreads();

    if (tid < NPAIR) {
        float s = 0.0f;
        #pragma unroll
        for (int w = 0; w < 16; ++w) s += redD[w][tid];
        Dt[tid] = s;
    } else if (tid >= 64 && tid < 64 + F) {
        const int f = tid - 64;
        float s = 0.0f;
        #pragma unroll
        for (int w = 0; w < 16; ++w) s += redT[w][f];
        Tt[f] = s;
    }
    __syncthreads();

    if (tid == 0) {
        const float invC  = 1.0f / (float)C;        // 2^-12, exact
        const float invC2 = invC * invC;            // 2^-24, exact
        float dcov[NPAIR], diag[F];
        int k = 0;
        for (int i = 0; i < F; ++i)
            for (int j = i; j < F; ++j) {
                // S_ij = G/C^2 - 2 D/C^3 + T_i T_j / C^4
                float S = Gs[k] * invC2 - 2.0f * Dt[k] * invC2 * invC +
                          (Tt[i] * invC2) * (Tt[j] * invC2);
                float dc = fast_sqrt(fmaxf(S, 0.0f) + EPSF);
                dcov[k] = dc;
                if (i == j) diag[i] = dc;
                ++k;
            }
        float cor = 0.0f;
        k = 0;
        for (int i = 0; i < F; ++i)
            for (int j = i; j < F; ++j) {
                if (j > i) cor += dcov[k] * __builtin_amdgcn_rcpf(
                                      fast_sqrt(diag[i] * diag[j] + EPSF));
                ++k;
            }
        out[0] = cor;
    }
}

extern "C" void kernel_launch(void* const* d_in, const int* in_sizes, int n_in,
                              void* d_out, int out_size, void* d_ws, size_t ws_size,
                              hipStream_t stream) {
    const float* x = (const float*)d_in[0];
    float* Gpart = (float*)d_ws;                 // [36][1024]
    float* spart = Gpart + NPAIR * NBLK;         // [4][8][4096]
    float* out   = (float*)d_out;

    hipLaunchKernelGGL(pair_kernel,   dim3(NBLK), dim3(256),  0, stream, x, Gpart, spart);
    hipLaunchKernelGGL(finish_kernel, dim3(1),    dim3(1024), 0, stream, Gpart, spart, out);
}

// Round 6
// 136.712 us; speedup vs baseline: 1.6446x; 1.6446x over previous
//
#include <hip/hip_runtime.h>
#include <hip/hip_bf16.h>
#include <math.h>

#define F 8
#define C 4096
#define NPAIR 36            // F*(F+1)/2 pairs with i<=j
#define EPSF 1e-8f
#define NBLKP 1024          // pair grid: 512 row-groups x 2 q-halves
#define QH 2048             // q-half length per block
#define QT 1024             // LDS q-tile; 8 * 1024 * 4B = 32 KB
#define NQD 2               // q-halves

// ws layout (floats):
//   Gpart : [NPAIR][NBLKP]   per-block partial G_ij       (36 K floats)
//   spart : [NQD][F][C]      half-partial row sums        (64 K floats)
// Every element is written by pair_kernel before finish_kernel reads it ->
// no zero-init needed, no atomics anywhere.

__device__ __forceinline__ float wave_reduce(float v) {
    #pragma unroll
    for (int off = 32; off > 0; off >>= 1) v += __shfl_down(v, off, 64);
    return v;
}

__device__ __forceinline__ float fast_sqrt(float v) {
    return __builtin_amdgcn_sqrtf(v);
}

// One q-point for 2 rows: 16 subs, 16 abs-adds, 72 FMAs (abs folds to VOP3
// source modifiers). d0/d1 are transient (8+8 regs).
__device__ __forceinline__ void do_point(const float vc[F],
                                         const float xp0[F], const float xp1[F],
                                         float rs0[F], float rs1[F],
                                         float g[NPAIR]) {
    float d0[F], d1[F];
    #pragma unroll
    for (int f = 0; f < F; ++f) {
        d0[f] = xp0[f] - vc[f];
        d1[f] = xp1[f] - vc[f];
        rs0[f] += __builtin_fabsf(d0[f]);
        rs1[f] += __builtin_fabsf(d1[f]);
    }
    int k = 0;
    #pragma unroll
    for (int i = 0; i < F; ++i)
        #pragma unroll
        for (int j = i; j < F; ++j) {
            g[k] = __builtin_fmaf(__builtin_fabsf(d0[i]), __builtin_fabsf(d0[j]), g[k]);
            g[k] = __builtin_fmaf(__builtin_fabsf(d1[i]), __builtin_fabsf(d1[j]), g[k]);
            ++k;
        }
}

// Each wave owns 2 rows and one q-half. The staged float4 v[8] feeds both
// rows (LDS bytes/position 32B -> 16B; 416 VALU insts of independent work
// per 8-load burst). Live regs: g36+rs16+xp16+v32+d16 ~ 118 -> no min-waves
// hint (R5's (256,4) hint made the allocator cap at 64 VGPRs and spill
// 640 MB to scratch).
__global__ __launch_bounds__(256) void pair_kernel(const float* __restrict__ x,
                                                   float* __restrict__ Gpart,
                                                   float* __restrict__ spart) {
    __shared__ __align__(16) float xs[F * QT];     // 32 KB
    __shared__ float red[4][NPAIR];
    const int tid  = threadIdx.x;
    const int lane = tid & 63;
    const int wave = tid >> 6;
    const int qh   = blockIdx.x >> 9;              // 0..1
    const int rg   = blockIdx.x & 511;             // row-group (8 rows)
    const int p0   = rg * 8 + wave * 2;            // this wave's 2 rows

    float xp0[F], xp1[F];
    #pragma unroll
    for (int f = 0; f < F; ++f) {
        xp0[f] = x[f * C + p0];
        xp1[f] = x[f * C + p0 + 1];
    }

    float g[NPAIR];
    #pragma unroll
    for (int k = 0; k < NPAIR; ++k) g[k] = 0.0f;
    float rs0[F], rs1[F];
    #pragma unroll
    for (int f = 0; f < F; ++f) { rs0[f] = 0.0f; rs1[f] = 0.0f; }

    const float4* xg = (const float4*)x;

    for (int tile = 0; tile < QH / QT; ++tile) {   // 2 tiles
        const int qb4 = (qh * QH + tile * QT) >> 2;
        __syncthreads();
        // stage 8 factors x 1024 floats = 2048 float4, 8 per thread
        for (int i = tid; i < F * (QT / 4); i += 256) {
            const int f  = i >> 8;                 // / (QT/4)
            const int q4 = i & (QT / 4 - 1);
            ((float4*)xs)[i] = xg[f * (C / 4) + qb4 + q4];
        }
        __syncthreads();

        for (int qt = 0; qt < QT / 4; qt += 64) {  // 4 iters
            const int qi = qt + lane;
            float4 v[F];
            #pragma unroll
            for (int f = 0; f < F; ++f) v[f] = ((const float4*)xs)[f * (QT / 4) + qi];

            float vc[F];
            #pragma unroll
            for (int f = 0; f < F; ++f) vc[f] = v[f].x;
            do_point(vc, xp0, xp1, rs0, rs1, g);
            #pragma unroll
            for (int f = 0; f < F; ++f) vc[f] = v[f].y;
            do_point(vc, xp0, xp1, rs0, rs1, g);
            #pragma unroll
            for (int f = 0; f < F; ++f) vc[f] = v[f].z;
            do_point(vc, xp0, xp1, rs0, rs1, g);
            #pragma unroll
            for (int f = 0; f < F; ++f) vc[f] = v[f].w;
            do_point(vc, xp0, xp1, rs0, rs1, g);
        }
    }

    // wave-level reduction (each wave owns its 2 rows exclusively)
    #pragma unroll
    for (int f = 0; f < F; ++f) { rs0[f] = wave_reduce(rs0[f]); rs1[f] = wave_reduce(rs1[f]); }
    #pragma unroll
    for (int k = 0; k < NPAIR; ++k) g[k] = wave_reduce(g[k]);

    if (lane == 0) {
        #pragma unroll
        for (int f = 0; f < F; ++f) {
            spart[(qh * F + f) * C + p0]     = rs0[f];
            spart[(qh * F + f) * C + p0 + 1] = rs1[f];
        }
        #pragma unroll
        for (int k = 0; k < NPAIR; ++k) red[wave][k] = g[k];
    }
    __syncthreads();
    if (tid < NPAIR)
        Gpart[tid * NBLKP + blockIdx.x] =
            red[0][tid] + red[1][tid] + red[2][tid] + red[3][tid];
}

// 1024 threads = 16 waves. Phase A: assemble full row sums from the 2
// half-partials, accumulate D (36 dots) and T (8 totals). Phase B: wave k
// reduces Gpart rows k, k+16, k+32. Scalar epilogue on t0.
__global__ __launch_bounds__(1024) void finish_kernel(const float* __restrict__ Gpart,
                                                      const float* __restrict__ spart,
                                                      float* __restrict__ out) {
    const int tid  = threadIdx.x;
    const int lane = tid & 63;
    const int wave = tid >> 6;      // 0..15

    __shared__ float redD[16][NPAIR];
    __shared__ float redT[16][F];
    __shared__ float Gs[NPAIR];
    __shared__ float Dt[NPAIR];
    __shared__ float Tt[F];

    float D[NPAIR], T[F];
    #pragma unroll
    for (int k = 0; k < NPAIR; ++k) D[k] = 0.0f;
    #pragma unroll
    for (int f = 0; f < F; ++f) T[f] = 0.0f;

    #pragma unroll
    for (int it = 0; it < C / 1024; ++it) {        // 4 iterations
        const int p = it * 1024 + tid;
        float sv[F];
        #pragma unroll
        for (int f = 0; f < F; ++f) {
            float s = spart[f * C + p];
            #pragma unroll
            for (int qd = 1; qd < NQD; ++qd) s += spart[(qd * F + f) * C + p];
            sv[f] = s;
            T[f] += s;
        }
        int k = 0;
        #pragma unroll
        for (int i = 0; i < F; ++i)
            #pragma unroll
            for (int j = i; j < F; ++j) { D[k] += sv[i] * sv[j]; ++k; }
    }
    #pragma unroll
    for (int k = 0; k < NPAIR; ++k) D[k] = wave_reduce(D[k]);
    #pragma unroll
    for (int f = 0; f < F; ++f) T[f] = wave_reduce(T[f]);
    if (lane == 0) {
        #pragma unroll
        for (int k = 0; k < NPAIR; ++k) redD[wave][k] = D[k];
        #pragma unroll
        for (int f = 0; f < F; ++f) redT[wave][f] = T[f];
    }

    // Phase B: G rows
    for (int k = wave; k < NPAIR; k += 16) {
        float s = 0.0f;
        #pragma unroll
        for (int it = 0; it < NBLKP / 64; ++it) s += Gpart[k * NBLKP + it * 64 + lane];
        s = wave_reduce(s);
        if (lane == 0) Gs[k] = s;
    }
    __syncthreads();

    if (tid < NPAIR) {
        float s = 0.0f;
        #pragma unroll
        for (int w = 0; w < 16; ++w) s += redD[w][tid];
        Dt[tid] = s;
    } else if (tid >= 64 && tid < 64 + F) {
        const int f = tid - 64;
        float s = 0.0f;
        #pragma unroll
        for (int w = 0; w < 16; ++w) s += redT[w][f];
        Tt[f] = s;
    }
    __syncthreads();

    if (tid == 0) {
        const float invC  = 1.0f / (float)C;        // 2^-12, exact
        const float invC2 = invC * invC;            // 2^-24, exact
        float dcov[NPAIR], diag[F];
        int k = 0;
        for (int i = 0; i < F; ++i)
            for (int j = i; j < F; ++j) {
                // S_ij = G/C^2 - 2 D/C^3 + T_i T_j / C^4
                float S = Gs[k] * invC2 - 2.0f * Dt[k] * invC2 * invC +
                          (Tt[i] * invC2) * (Tt[j] * invC2);
                float dc = fast_sqrt(fmaxf(S, 0.0f) + EPSF);
                dcov[k] = dc;
                if (i == j) diag[i] = dc;
                ++k;
            }
        float cor = 0.0f;
        k = 0;
        for (int i = 0; i < F; ++i)
            for (int j = i; j < F; ++j) {
                if (j > i) cor += dcov[k] * __builtin_amdgcn_rcpf(
                                      fast_sqrt(diag[i] * diag[j] + EPSF));
                ++k;
            }
        out[0] = cor;
    }
}

extern "C" void kernel_launch(void* const* d_in, const int* in_sizes, int n_in,
                              void* d_out, int out_size, void* d_ws, size_t ws_size,
                              hipStream_t stream) {
    const float* x = (const float*)d_in[0];
    float* Gpart = (float*)d_ws;                 // [36][1024]
    float* spart = Gpart + NPAIR * NBLKP;        // [2][8][4096]
    float* out   = (float*)d_out;

    hipLaunchKernelGGL(pair_kernel,   dim3(NBLKP), dim3(256),  0, stream, x, Gpart, spart);
    hipLaunchKernelGGL(finish_kernel, dim3(1),     dim3(1024), 0, stream, Gpart, spart, out);
}